// Round 6
// baseline (239.279 us; speedup 1.0000x reference)
//
#include <hip/hip_runtime.h>

#define RAW 256
#define LAT 100
#define LAT2 200
#define NCLS 55
#define FDIM 64    // padded row: 0..54 classes, 55 ones-col, 56..63 zero (fp16 row = 128 B = 1 line)
#define GR 64      // rows per gemm block (MFMA path: 4 waves x one 16-row tile, no LDS)
#define CAP 64     // padded-CSR capacity per node (front = src<N/2, back = src>=N/2)
#define BSH 8      // bucket = dst >> 8 (256 nodes per bucket)
#define BNODES 256
#define NBUK 256   // max bucket count (196 used at N=50000)
#define BCAP 5120  // per-bucket edge capacity (mean 4096, +16 sigma)
#define EPB 2048   // edges per bin block (round-3 config: 11 KB LDS, best measured)

typedef _Float16 h8 __attribute__((ext_vector_type(8)));
typedef float f32x4 __attribute__((ext_vector_type(4)));
typedef unsigned int u32x4 __attribute__((ext_vector_type(4)));

// ---- wave-per-row small-GEMM helpers (lane j = output col, 64-wide padded B) ----
__device__ __forceinline__ float dotrow(const float* __restrict__ Arow,
                                        const float* __restrict__ Bp, int K, int j) {
  float a0 = 0.f, a1 = 0.f, a2 = 0.f, a3 = 0.f;
  int k = 0;
  for (; k + 3 < K; k += 4) {
    a0 += Arow[k + 0] * Bp[(k + 0) * 64 + j];
    a1 += Arow[k + 1] * Bp[(k + 1) * 64 + j];
    a2 += Arow[k + 2] * Bp[(k + 2) * 64 + j];
    a3 += Arow[k + 3] * Bp[(k + 3) * 64 + j];
  }
  for (; k < K; ++k) a0 += Arow[k] * Bp[k * 64 + j];
  return (a0 + a1) + (a2 + a3);
}

__device__ __forceinline__ float dotrow_wc(const float* __restrict__ Arow,
                                           const float* __restrict__ Wc, int K, int j) {
  if (j >= NCLS) return 0.f;
  float a0 = 0.f, a1 = 0.f, a2 = 0.f, a3 = 0.f;
  for (int k = 0; k + 3 < K; k += 4) {
    a0 += Arow[k + 0] * Wc[(k + 0) * NCLS + j];
    a1 += Arow[k + 1] * Wc[(k + 1) * NCLS + j];
    a2 += Arow[k + 2] * Wc[(k + 2) * NCLS + j];
    a3 += Arow[k + 3] * Wc[(k + 3) * NCLS + j];
  }
  return (a0 + a1) + (a2 + a3);
}

// ---------------- weight chain (3 tiny stream-ordered kernels) ----------------
__global__ __launch_bounds__(256) void w1_kernel(const float* __restrict__ W2,
                                                 const float* __restrict__ b2,
                                                 const float* __restrict__ Wc,
                                                 float* __restrict__ T1p,
                                                 float* __restrict__ cvec) {
  int task = blockIdx.x * 4 + (threadIdx.x >> 6);
  int j = threadIdx.x & 63;
  if (task < LAT)
    T1p[task * 64 + j] = dotrow_wc(&W2[task * LAT2], Wc, LAT2, j);
  else if (task == LAT)
    cvec[128 + j] = dotrow_wc(b2, Wc, LAT2, j);  // c0
}

__global__ __launch_bounds__(256) void w2_kernel(const float* __restrict__ W1,
                                                 const float* __restrict__ b1,
                                                 const float* __restrict__ T1p,
                                                 float* __restrict__ T2p,
                                                 float* __restrict__ cvec) {
  int task = blockIdx.x * 4 + (threadIdx.x >> 6);
  int j = threadIdx.x & 63;
  if (task < LAT)
    T2p[task * 64 + j] = dotrow(&W1[task * LAT], T1p, LAT, j);
  else if (task == LAT)
    cvec[64 + j] = dotrow(b1, T1p, LAT, j);  // c1
}

// w3 emits the fused extractor weight TRANSPOSED in fp16: Wt[col][k], 64x256 (32 KB).
__global__ __launch_bounds__(256) void w3_kernel(const float* __restrict__ W_ext,
                                                 const float* __restrict__ b_ext,
                                                 const float* __restrict__ T2p,
                                                 _Float16* __restrict__ Wt,
                                                 float* __restrict__ cvec) {
  int task = blockIdx.x * 4 + (threadIdx.x >> 6);
  int j = threadIdx.x & 63;
  if (task < RAW)
    Wt[(size_t)j * RAW + task] = (_Float16)dotrow(&W_ext[task * LAT], T2p, LAT, j);
  else if (task == RAW)
    cvec[j] = dotrow(b_ext, T2p, LAT, j);  // c2
}

// ---------------- mega: bin blocks (round-3 coalesced binning) ∥ MFMA gemm blocks ----------------
__global__ __launch_bounds__(256) void mega(
    const int* __restrict__ src, const int* __restrict__ dst,
    int* deg_o, int* gcur, unsigned int* __restrict__ gedges, int E,
    const float* __restrict__ X, const _Float16* __restrict__ Wt,
    _Float16* __restrict__ Y, int N, int nE, int nGm) {
  __shared__ unsigned int stage[EPB];   // 8 KB
  __shared__ int cnt[NBUK], off[NBUK], gbase[NBUK];  // 3 KB
  int b = blockIdx.x;
  int t = threadIdx.x;
  int total = nE + nGm;
  long long lo = (long long)b * nGm / total;
  long long hi = (long long)(b + 1) * nGm / total;
  if (hi == lo) {
    // ---- bin block ----
    int blk = b - (int)lo;
    int e0 = blk * EPB;
    cnt[t] = 0;
    __syncthreads();
    unsigned int pk[8];
    int rk[8], bk[8];
#pragma unroll
    for (int i = 0; i < 8; ++i) {
      int e = e0 + t + 256 * i;
      pk[i] = 0xFFFFFFFFu;
      if (e < E) {
        int s = src[e];
        int d = dst[e];
        atomicAdd(&deg_o[s], 1);
        pk[i] = ((unsigned int)d << 16) | (unsigned int)s;
        bk[i] = d >> BSH;
        rk[i] = atomicAdd(&cnt[bk[i]], 1);
      }
    }
    __syncthreads();
    if (t == 0) {
      int run = 0;
      for (int i = 0; i < NBUK; ++i) { off[i] = run; run += cnt[i]; }
    }
    __syncthreads();
    if (cnt[t] > 0) gbase[t] = atomicAdd(&gcur[t], cnt[t]);
    __syncthreads();
#pragma unroll
    for (int i = 0; i < 8; ++i)
      if (pk[i] != 0xFFFFFFFFu) stage[off[bk[i]] + rk[i]] = pk[i];
    __syncthreads();
    int totE = min(EPB, E - e0);
    for (int p = t; p < totE; p += 256) {
      unsigned int v = stage[p];
      int bb = (int)(v >> 16) >> BSH;
      int idx = gbase[bb] + (p - off[bb]);
      if (idx < BCAP) gedges[(size_t)bb * BCAP + idx] = v;
    }
    return;
  }
  // ---- gemm block (MFMA) ----
  int r0 = (int)lo * GR;
  int w = t >> 6;            // wave id -> 16-row tile
  int l = t & 63;
  int lr = l & 15;           // A row-in-tile / B,D col-in-tile
  int g = l >> 4;            // k-group (8 elems each)
  int gr = r0 + w * 16 + lr;
  int grc = gr < N ? gr : N - 1;  // clamp; garbage rows never stored
  const float* __restrict__ Xrow = &X[(size_t)grc * RAW];
  const _Float16* __restrict__ Wb = &Wt[(size_t)lr * RAW];  // col lr of tile 0
  f32x4 acc0 = {0.f, 0.f, 0.f, 0.f};
  f32x4 acc1 = {0.f, 0.f, 0.f, 0.f};
  f32x4 acc2 = {0.f, 0.f, 0.f, 0.f};
  f32x4 acc3 = {0.f, 0.f, 0.f, 0.f};
#pragma unroll
  for (int kk = 0; kk < 8; ++kk) {
    int kb = kk * 32 + g * 8;
    float4 xa = *(const float4*)&Xrow[kb];
    float4 xb = *(const float4*)&Xrow[kb + 4];
    h8 a;
    a[0] = (_Float16)xa.x; a[1] = (_Float16)xa.y;
    a[2] = (_Float16)xa.z; a[3] = (_Float16)xa.w;
    a[4] = (_Float16)xb.x; a[5] = (_Float16)xb.y;
    a[6] = (_Float16)xb.z; a[7] = (_Float16)xb.w;
    h8 b0 = *(const h8*)&Wb[kb];                 // cols  0..15
    h8 b1 = *(const h8*)&Wb[16 * RAW + kb];      // cols 16..31
    h8 b2 = *(const h8*)&Wb[32 * RAW + kb];      // cols 32..47
    h8 b3 = *(const h8*)&Wb[48 * RAW + kb];      // cols 48..63
    acc0 = __builtin_amdgcn_mfma_f32_16x16x32_f16(a, b0, acc0, 0, 0, 0);
    acc1 = __builtin_amdgcn_mfma_f32_16x16x32_f16(a, b1, acc1, 0, 0, 0);
    acc2 = __builtin_amdgcn_mfma_f32_16x16x32_f16(a, b2, acc2, 0, 0, 0);
    acc3 = __builtin_amdgcn_mfma_f32_16x16x32_f16(a, b3, acc3, 0, 0, 0);
  }
#pragma unroll
  for (int r = 0; r < 4; ++r) {
    int row = r0 + w * 16 + g * 4 + r;
    if (row < N) {
      _Float16* yr = &Y[(size_t)row * FDIM];
      yr[lr] = (_Float16)acc0[r];
      yr[16 + lr] = (_Float16)acc1[r];
      yr[32 + lr] = (_Float16)acc2[r];
      int c3 = 48 + lr;   // col 55 -> ones; 56..63 acc is exactly 0 (Wt rows zero)
      yr[c3] = (c3 == NCLS) ? (_Float16)1.f : (_Float16)acc3[r];
    }
  }
}

// ---------------- build_scale: per-bucket CSR build in LDS + fold of scaleY ----------------
__global__ __launch_bounds__(256) void build_scale(
    const unsigned int* __restrict__ gedges, const int* __restrict__ gcur,
    unsigned short* __restrict__ csr_pad, int* __restrict__ fill_lo,
    int* __restrict__ fill_hi, _Float16* __restrict__ Y,
    const int* __restrict__ deg_o, int N) {
  __shared__ __align__(16) unsigned short tile[BNODES * CAP];  // 32 KB
  __shared__ int flo[BNODES], fhi[BNODES];                     // 2 KB
  int b = blockIdx.x;
  int t = threadIdx.x;
  flo[t] = 0; fhi[t] = 0;
  __syncthreads();
  int cnt = min(gcur[b], BCAP);
  int half = N >> 1;
  int nbeg = b << BSH;
  const unsigned int* ge = &gedges[(size_t)b * BCAP];
  for (int i = t; i < cnt; i += 256) {
    unsigned int v = ge[i];
    int s = (int)(v & 0xFFFFu);
    int ln = ((int)(v >> 16)) - nbeg;
    if (s < half) {
      int r = atomicAdd(&flo[ln], 1);
      if (r < CAP) tile[ln * CAP + r] = (unsigned short)s;
    } else {
      int r = atomicAdd(&fhi[ln], 1);
      int pos = CAP - 1 - r;
      if (pos >= 0) tile[ln * CAP + pos] = (unsigned short)s;
    }
  }
  __syncthreads();
  int nn = min(BNODES, N - nbeg);
  if (nn <= 0) return;
  // coalesced CSR write-out: nn rows x 128 B (uninitialized slots are garbage, never read)
  const uint4* tl = (const uint4*)tile;
  uint4* gp = (uint4*)&csr_pad[(size_t)nbeg * CAP];
  for (int u = t; u < nn * 8; u += 256) gp[u] = tl[u];
  if (t < nn) {
    fill_lo[nbeg + t] = flo[t];
    fill_hi[nbeg + t] = fhi[t];
  }
  // fold scaleY for this node range: one h8 (16 B) per thread-iter
  for (int idx = t; idx < nn * 8; idx += 256) {
    int n = nbeg + (idx >> 3);
    int c = (idx & 7) * 8;
    float w = 1.f / sqrtf(fmaxf((float)deg_o[n], 1.f));
    h8 v = *(h8*)&Y[(size_t)n * FDIM + c];
#pragma unroll
    for (int q = 0; q < 8; ++q) v[q] = (_Float16)((float)v[q] * w);
    *(h8*)&Y[(size_t)n * FDIM + c] = v;
  }
}

// ---------------- agg1: LDS-staged indices + 8-deep gather; B = s_mid(n)·Σ Y[s] ----------------
// Index tile (32 nodes x 128 B) staged via nontemporal u32x4 into padded LDS rows (144 B) ->
// index reads are LDS broadcasts (no dependent global loads); 8 gathers of 128-B rows in flight.
__global__ __launch_bounds__(256) void agg1_kernel(const _Float16* __restrict__ Y,
    const unsigned short* __restrict__ csr_pad,
    const int* __restrict__ fill_lo, const int* __restrict__ fill_hi,
    const int* __restrict__ deg_o, _Float16* __restrict__ B,
    float* __restrict__ u_out, int N) {
  __shared__ __align__(16) unsigned short lidx[32][72];  // 4.5 KB, row = 144 B (16-mult, bank-safe)
  __shared__ int sflo[32], sfhi[32], sdeg[32];
  int t = threadIdx.x;
  int n0 = blockIdx.x * 32;
  {
    int nn8 = (min(32, N - n0)) * 8;
    if (t < nn8) {
      const u32x4* csr4 = (const u32x4*)&csr_pad[(size_t)n0 * CAP];
      u32x4 v = __builtin_nontemporal_load(&csr4[t]);
      *(u32x4*)&lidx[t >> 3][(t & 7) * 8] = v;
    }
    if (t < 32 && n0 + t < N) {
      sflo[t] = fill_lo[n0 + t];
      sfhi[t] = fill_hi[n0 + t];
      sdeg[t] = deg_o[n0 + t];
    }
  }
  __syncthreads();
  int ln = t >> 3;
  int n = n0 + ln;
  int l = t & 7;                             // cols 8l..8l+7
  if (n >= N) return;
  int flo = min(sflo[ln], CAP);
  int fhi = min(sfhi[ln], CAP);
  int fi = sflo[ln] + sfhi[ln];
  const unsigned short* lst = lidx[ln];
  float A0[8], A1[8];
#pragma unroll
  for (int q = 0; q < 8; ++q) { A0[q] = 0.f; A1[q] = 0.f; }
#pragma unroll 1
  for (int sw = 0; sw < 2; ++sw) {
    int i = sw ? (CAP - fhi) : 0;
    int end = sw ? CAP : flo;
    for (; i + 7 < end; i += 8) {
      int s[8];
#pragma unroll
      for (int u = 0; u < 8; ++u) s[u] = lst[i + u];
      h8 v[8];
#pragma unroll
      for (int u = 0; u < 8; ++u) v[u] = *(const h8*)&Y[(size_t)s[u] * FDIM + 8 * l];
#pragma unroll
      for (int q = 0; q < 8; ++q) {
        A0[q] += ((float)v[0][q] + (float)v[2][q]) + ((float)v[4][q] + (float)v[6][q]);
        A1[q] += ((float)v[1][q] + (float)v[3][q]) + ((float)v[5][q] + (float)v[7][q]);
      }
    }
    for (; i + 3 < end; i += 4) {
      int s0 = lst[i], s1 = lst[i + 1], s2 = lst[i + 2], s3 = lst[i + 3];
      h8 v0 = *(const h8*)&Y[(size_t)s0 * FDIM + 8 * l];
      h8 v1 = *(const h8*)&Y[(size_t)s1 * FDIM + 8 * l];
      h8 v2 = *(const h8*)&Y[(size_t)s2 * FDIM + 8 * l];
      h8 v3 = *(const h8*)&Y[(size_t)s3 * FDIM + 8 * l];
#pragma unroll
      for (int q = 0; q < 8; ++q) {
        A0[q] += (float)v0[q] + (float)v2[q];
        A1[q] += (float)v1[q] + (float)v3[q];
      }
    }
    for (; i < end; ++i) {
      h8 v = *(const h8*)&Y[(size_t)lst[i] * FDIM + 8 * l];
#pragma unroll
      for (int q = 0; q < 8; ++q) A0[q] += (float)v[q];
    }
  }
  float inv_i = 1.f / sqrtf(fmaxf((float)fi, 1.f));
  float inv_on = 1.f / sqrtf(fmaxf((float)sdeg[ln], 1.f));
  float sm = inv_i * inv_on;                 // next layer's inv_o pre-applied
  h8 o;
#pragma unroll
  for (int q = 0; q < 8; ++q) o[q] = (_Float16)((A0[q] + A1[q]) * sm);
  *(h8*)&B[(size_t)n * FDIM + 8 * l] = o;    // cached store: agg2 gathers from B
  if (l == 6) u_out[n] = (A0[7] + A1[7]) * inv_i;  // col 55 = lane 6, comp 7
}

// ---------------- agg2: LDS-staged indices + 8-deep gather; bufA fp32 = inv_i(n)·Σ B[s] ----------------
__global__ __launch_bounds__(256) void agg2_kernel(const _Float16* __restrict__ B,
    const unsigned short* __restrict__ csr_pad,
    const int* __restrict__ fill_lo, const int* __restrict__ fill_hi,
    float* __restrict__ bufA, int N) {
  __shared__ __align__(16) unsigned short lidx[32][72];
  __shared__ int sflo[32], sfhi[32];
  int t = threadIdx.x;
  int n0 = blockIdx.x * 32;
  {
    int nn8 = (min(32, N - n0)) * 8;
    if (t < nn8) {
      const u32x4* csr4 = (const u32x4*)&csr_pad[(size_t)n0 * CAP];
      u32x4 v = __builtin_nontemporal_load(&csr4[t]);
      *(u32x4*)&lidx[t >> 3][(t & 7) * 8] = v;
    }
    if (t < 32 && n0 + t < N) {
      sflo[t] = fill_lo[n0 + t];
      sfhi[t] = fill_hi[n0 + t];
    }
  }
  __syncthreads();
  int ln = t >> 3;
  int n = n0 + ln;
  int l = t & 7;
  if (n >= N) return;
  int flo = min(sflo[ln], CAP);
  int fhi = min(sfhi[ln], CAP);
  int fi = sflo[ln] + sfhi[ln];
  const unsigned short* lst = lidx[ln];
  float A0[8], A1[8];
#pragma unroll
  for (int q = 0; q < 8; ++q) { A0[q] = 0.f; A1[q] = 0.f; }
#pragma unroll 1
  for (int sw = 0; sw < 2; ++sw) {
    int i = sw ? (CAP - fhi) : 0;
    int end = sw ? CAP : flo;
    for (; i + 7 < end; i += 8) {
      int s[8];
#pragma unroll
      for (int u = 0; u < 8; ++u) s[u] = lst[i + u];
      h8 v[8];
#pragma unroll
      for (int u = 0; u < 8; ++u) v[u] = *(const h8*)&B[(size_t)s[u] * FDIM + 8 * l];
#pragma unroll
      for (int q = 0; q < 8; ++q) {
        A0[q] += ((float)v[0][q] + (float)v[2][q]) + ((float)v[4][q] + (float)v[6][q]);
        A1[q] += ((float)v[1][q] + (float)v[3][q]) + ((float)v[5][q] + (float)v[7][q]);
      }
    }
    for (; i + 3 < end; i += 4) {
      int s0 = lst[i], s1 = lst[i + 1], s2 = lst[i + 2], s3 = lst[i + 3];
      h8 v0 = *(const h8*)&B[(size_t)s0 * FDIM + 8 * l];
      h8 v1 = *(const h8*)&B[(size_t)s1 * FDIM + 8 * l];
      h8 v2 = *(const h8*)&B[(size_t)s2 * FDIM + 8 * l];
      h8 v3 = *(const h8*)&B[(size_t)s3 * FDIM + 8 * l];
#pragma unroll
      for (int q = 0; q < 8; ++q) {
        A0[q] += (float)v0[q] + (float)v2[q];
        A1[q] += (float)v1[q] + (float)v3[q];
      }
    }
    for (; i < end; ++i) {
      h8 v = *(const h8*)&B[(size_t)lst[i] * FDIM + 8 * l];
#pragma unroll
      for (int q = 0; q < 8; ++q) A0[q] += (float)v[q];
    }
  }
  float inv_i = 1.f / sqrtf(fmaxf((float)fi, 1.f));
  f32x4 o0, o1;
  o0[0] = (A0[0] + A1[0]) * inv_i; o0[1] = (A0[1] + A1[1]) * inv_i;
  o0[2] = (A0[2] + A1[2]) * inv_i; o0[3] = (A0[3] + A1[3]) * inv_i;
  o1[0] = (A0[4] + A1[4]) * inv_i; o1[1] = (A0[5] + A1[5]) * inv_i;
  o1[2] = (A0[6] + A1[6]) * inv_i; o1[3] = (A0[7] + A1[7]) * inv_i;
  __builtin_nontemporal_store(o0, (f32x4*)&bufA[(size_t)n * FDIM + 8 * l]);
  __builtin_nontemporal_store(o1, (f32x4*)&bufA[(size_t)n * FDIM + 8 * l + 4]);
}

// ---------------- pool + combine ----------------
__global__ __launch_bounds__(256) void pool_final(const float* __restrict__ feat,
    const float* __restrict__ u, const int* __restrict__ gid,
    const float* __restrict__ cvec, const float* __restrict__ bc,
    float* __restrict__ out, int N, int G) {
  __shared__ int sb[2];
  __shared__ float red[4][64];
  int g = blockIdx.x;
  int t = threadIdx.x;
  int rg = t >> 6, j = t & 63;
  if (t < 2) {
    int target = g + t;
    int lo = 0, hi = N;
    while (lo < hi) {
      int mid = (lo + hi) >> 1;
      if (gid[mid] < target) lo = mid + 1; else hi = mid;
    }
    sb[t] = lo;
  }
  __syncthreads();
  int beg = sb[0], end = sb[1];
  float acc = 0.f;
  for (int r = beg + rg; r < end; r += 4) {
    float v;
    if (j < NCLS + 1) v = feat[(size_t)r * FDIM + j];
    else if (j == NCLS + 1) v = u[r];
    else v = 0.f;
    acc += v;
  }
  red[rg][j] = acc;
  __syncthreads();
  if (rg == 0) {
    float s = red[0][j] + red[1][j] + red[2][j] + red[3][j];
    float cnt = (float)(end - beg);
    float inv = 1.f / fmaxf(cnt, 1.f);
    red[1][j] = s * inv;
  }
  __syncthreads();
  if (rg == 0 && j < NCLS) {
    float vbar = red[1][NCLS];
    float ubar = red[1][NCLS + 1];
    float ind = (end > beg) ? 1.f : 0.f;
    out[g * NCLS + j] = red[1][j] + vbar * cvec[j] + ubar * cvec[64 + j]
                        + ind * cvec[128 + j] + bc[j];
  }
}

extern "C" void kernel_launch(void* const* d_in, const int* in_sizes, int n_in,
                              void* d_out, int out_size, void* d_ws, size_t ws_size,
                              hipStream_t stream) {
  const float* X     = (const float*)d_in[0];
  const int*   src   = (const int*)d_in[1];
  const int*   dst   = (const int*)d_in[2];
  const int*   gid   = (const int*)d_in[3];
  const float* W_ext = (const float*)d_in[4];
  const float* b_ext = (const float*)d_in[5];
  const float* W1    = (const float*)d_in[6];
  const float* b1    = (const float*)d_in[7];
  const float* W2    = (const float*)d_in[8];
  const float* b2    = (const float*)d_in[9];
  const float* Wc    = (const float*)d_in[10];
  const float* bc    = (const float*)d_in[11];
  float* out = (float*)d_out;

  int N = in_sizes[0] / RAW;
  int E = in_sizes[1];
  int G = out_size / NCLS;
  int nb = (N + BNODES - 1) >> BSH;   // 196 buckets for N=50000

  char* p = (char*)d_ws;
  auto alloc = [&](size_t b) { char* r = p; p += (b + 255) & ~(size_t)255; return r; };

  int*            deg_o   = (int*)alloc((size_t)N * 4);
  int*            gcur    = (int*)alloc(NBUK * 4);
  size_t zero_span = (size_t)(p - (char*)deg_o);
  int*            fill_lo = (int*)alloc((size_t)N * 4);
  int*            fill_hi = (int*)alloc((size_t)N * 4);
  unsigned short* csr_pad = (unsigned short*)alloc((size_t)N * CAP * 2);
  unsigned int*   gedges  = (unsigned int*)alloc((size_t)nb * BCAP * 4);
  float*          T1p     = (float*)alloc(LAT * 64 * 4);
  float*          T2p     = (float*)alloc(LAT * 64 * 4);
  _Float16*       Wt      = (_Float16*)alloc((size_t)64 * RAW * 2);
  float*          cvec    = (float*)alloc(192 * 4);
  float*          u_arr   = (float*)alloc((size_t)N * 4);
  _Float16*       Y       = (_Float16*)alloc((size_t)N * FDIM * 2);
  _Float16*       B       = (_Float16*)alloc((size_t)N * FDIM * 2);
  float*          bufA    = (float*)alloc((size_t)N * FDIM * 4);

  hipMemsetAsync(deg_o, 0, zero_span, stream);

  w1_kernel<<<(LAT + 1 + 3) / 4, 256, 0, stream>>>(W2, b2, Wc, T1p, cvec);
  w2_kernel<<<(LAT + 1 + 3) / 4, 256, 0, stream>>>(W1, b1, T1p, T2p, cvec);
  w3_kernel<<<(RAW + 1 + 3) / 4, 256, 0, stream>>>(W_ext, b_ext, T2p, Wt, cvec);

  int nE = (E + EPB - 1) / EPB;
  int nGm = (N + GR - 1) / GR;
  mega<<<nE + nGm, 256, 0, stream>>>(src, dst, deg_o, gcur, gedges, E,
                                     X, Wt, Y, N, nE, nGm);

  build_scale<<<nb, 256, 0, stream>>>(gedges, gcur, csr_pad, fill_lo, fill_hi,
                                      Y, deg_o, N);

  int aggGrid = (N + 31) / 32;
  agg1_kernel<<<aggGrid, 256, 0, stream>>>(Y, csr_pad, fill_lo, fill_hi, deg_o, B, u_arr, N);
  agg2_kernel<<<aggGrid, 256, 0, stream>>>(B, csr_pad, fill_lo, fill_hi, bufA, N);

  pool_final<<<G, 256, 0, stream>>>(bufA, u_arr, gid, cvec, bc, out, N, G);
}

// Round 7
// 211.290 us; speedup vs baseline: 1.1325x; 1.1325x over previous
//
#include <hip/hip_runtime.h>

#define RAW 256
#define LAT 100
#define LAT2 200
#define NCLS 55
#define FDIM 64    // padded row: 0..54 classes, 55 ones-col, 56..63 zero (fp16 row = 128 B = 1 line)
#define GR 64      // rows per gemm block (MFMA path: 4 waves x one 16-row tile, no LDS)
#define CAP 64     // padded-CSR capacity per node (front = src<N/2, back = src>=N/2)
#define BSH 8      // bucket = node >> 8 (256 nodes per bucket)
#define BNODES 256
#define NBUK 256   // max bucket count (196 used at N=50000)
#define BCAP 5120  // per-bucket edge capacity (mean 4096, +16 sigma)
#define EPB 2048   // edges per bin block (round-3 config: best measured)

typedef _Float16 h8 __attribute__((ext_vector_type(8)));
typedef float f32x4 __attribute__((ext_vector_type(4)));

// ---- wave-per-row small-GEMM helpers (lane j = output col, 64-wide padded B) ----
__device__ __forceinline__ float dotrow(const float* __restrict__ Arow,
                                        const float* __restrict__ Bp, int K, int j) {
  float a0 = 0.f, a1 = 0.f, a2 = 0.f, a3 = 0.f;
  int k = 0;
  for (; k + 3 < K; k += 4) {
    a0 += Arow[k + 0] * Bp[(k + 0) * 64 + j];
    a1 += Arow[k + 1] * Bp[(k + 1) * 64 + j];
    a2 += Arow[k + 2] * Bp[(k + 2) * 64 + j];
    a3 += Arow[k + 3] * Bp[(k + 3) * 64 + j];
  }
  for (; k < K; ++k) a0 += Arow[k] * Bp[k * 64 + j];
  return (a0 + a1) + (a2 + a3);
}

__device__ __forceinline__ float dotrow_wc(const float* __restrict__ Arow,
                                           const float* __restrict__ Wc, int K, int j) {
  if (j >= NCLS) return 0.f;
  float a0 = 0.f, a1 = 0.f, a2 = 0.f, a3 = 0.f;
  for (int k = 0; k + 3 < K; k += 4) {
    a0 += Arow[k + 0] * Wc[(k + 0) * NCLS + j];
    a1 += Arow[k + 1] * Wc[(k + 1) * NCLS + j];
    a2 += Arow[k + 2] * Wc[(k + 2) * NCLS + j];
    a3 += Arow[k + 3] * Wc[(k + 3) * NCLS + j];
  }
  return (a0 + a1) + (a2 + a3);
}

// ---------------- weight chain (3 tiny stream-ordered kernels) ----------------
__global__ __launch_bounds__(256) void w1_kernel(const float* __restrict__ W2,
                                                 const float* __restrict__ b2,
                                                 const float* __restrict__ Wc,
                                                 float* __restrict__ T1p,
                                                 float* __restrict__ cvec) {
  int task = blockIdx.x * 4 + (threadIdx.x >> 6);
  int j = threadIdx.x & 63;
  if (task < LAT)
    T1p[task * 64 + j] = dotrow_wc(&W2[task * LAT2], Wc, LAT2, j);
  else if (task == LAT)
    cvec[128 + j] = dotrow_wc(b2, Wc, LAT2, j);  // c0
}

__global__ __launch_bounds__(256) void w2_kernel(const float* __restrict__ W1,
                                                 const float* __restrict__ b1,
                                                 const float* __restrict__ T1p,
                                                 float* __restrict__ T2p,
                                                 float* __restrict__ cvec) {
  int task = blockIdx.x * 4 + (threadIdx.x >> 6);
  int j = threadIdx.x & 63;
  if (task < LAT)
    T2p[task * 64 + j] = dotrow(&W1[task * LAT], T1p, LAT, j);
  else if (task == LAT)
    cvec[64 + j] = dotrow(b1, T1p, LAT, j);  // c1
}

// w3 emits the fused extractor weight TRANSPOSED in fp16: Wt[col][k], 64x256 (32 KB).
__global__ __launch_bounds__(256) void w3_kernel(const float* __restrict__ W_ext,
                                                 const float* __restrict__ b_ext,
                                                 const float* __restrict__ T2p,
                                                 _Float16* __restrict__ Wt,
                                                 float* __restrict__ cvec) {
  int task = blockIdx.x * 4 + (threadIdx.x >> 6);
  int j = threadIdx.x & 63;
  if (task < RAW)
    Wt[(size_t)j * RAW + task] = (_Float16)dotrow(&W_ext[task * LAT], T2p, LAT, j);
  else if (task == RAW)
    cvec[j] = dotrow(b_ext, T2p, LAT, j);  // c2
}

// ---------------- mega: bin blocks (dual counting sort, NO global atomics) ∥ MFMA gemm blocks ------
// Pass A bins edges by dst>>8 into gedges (packed dst16|src16) for the CSR build; pass B re-bins the
// SAME edges (still in registers) by src>>8 into gsrc (value=src) for the out-degree histogram.
// deg_o global atomics are GONE — out-degree is recovered per-bucket in build_scale via LDS atomics.
// gemm half: Y[N][64] fp16 = [X @ Wall | 1 | 0] via v_mfma_f32_16x16x32_f16, no LDS.
__global__ __launch_bounds__(256) void mega(
    const int* __restrict__ src, const int* __restrict__ dst,
    int* gcur, int* gcur2, unsigned int* __restrict__ gedges,
    unsigned int* __restrict__ gsrc, int E,
    const float* __restrict__ X, const _Float16* __restrict__ Wt,
    _Float16* __restrict__ Y, int N, int nE, int nGm) {
  __shared__ unsigned int stage[EPB];   // 8 KB
  __shared__ int cnt[NBUK], off[NBUK], gbase[NBUK];  // 3 KB
  int b = blockIdx.x;
  int t = threadIdx.x;
  int total = nE + nGm;
  long long lo = (long long)b * nGm / total;
  long long hi = (long long)(b + 1) * nGm / total;
  if (hi == lo) {
    // ---- bin block ----
    int blk = b - (int)lo;
    int e0 = blk * EPB;
    int totE = min(EPB, E - e0);
    cnt[t] = 0;
    __syncthreads();
    unsigned int pk[8];
    int rk[8], bk[8];
    // ---- pass A: bin by dst ----
#pragma unroll
    for (int i = 0; i < 8; ++i) {
      int e = e0 + t + 256 * i;
      pk[i] = 0xFFFFFFFFu;
      if (e < E) {
        int s = src[e];
        int d = dst[e];
        pk[i] = ((unsigned int)d << 16) | (unsigned int)s;
        bk[i] = d >> BSH;
        rk[i] = atomicAdd(&cnt[bk[i]], 1);
      }
    }
    __syncthreads();
    if (t == 0) {
      int run = 0;
      for (int i = 0; i < NBUK; ++i) { off[i] = run; run += cnt[i]; }
    }
    __syncthreads();
    if (cnt[t] > 0) gbase[t] = atomicAdd(&gcur[t], cnt[t]);
    __syncthreads();
#pragma unroll
    for (int i = 0; i < 8; ++i)
      if (pk[i] != 0xFFFFFFFFu) stage[off[bk[i]] + rk[i]] = pk[i];
    __syncthreads();
    for (int p = t; p < totE; p += 256) {
      unsigned int v = stage[p];
      int bb = (int)(v >> 16) >> BSH;
      int idx = gbase[bb] + (p - off[bb]);
      if (idx < BCAP) gedges[(size_t)bb * BCAP + idx] = v;
    }
    // ---- pass B: bin by src (for out-degree); edges still in pk[] ----
    __syncthreads();
    cnt[t] = 0;
    __syncthreads();
#pragma unroll
    for (int i = 0; i < 8; ++i) {
      if (pk[i] != 0xFFFFFFFFu) {
        bk[i] = (int)(pk[i] & 0xFFFFu) >> BSH;
        rk[i] = atomicAdd(&cnt[bk[i]], 1);
      }
    }
    __syncthreads();
    if (t == 0) {
      int run = 0;
      for (int i = 0; i < NBUK; ++i) { off[i] = run; run += cnt[i]; }
    }
    __syncthreads();
    if (cnt[t] > 0) gbase[t] = atomicAdd(&gcur2[t], cnt[t]);
    __syncthreads();
#pragma unroll
    for (int i = 0; i < 8; ++i)
      if (pk[i] != 0xFFFFFFFFu) stage[off[bk[i]] + rk[i]] = pk[i] & 0xFFFFu;
    __syncthreads();
    for (int p = t; p < totE; p += 256) {
      unsigned int v = stage[p];           // v = src value
      int bb = (int)v >> BSH;
      int idx = gbase[bb] + (p - off[bb]);
      if (idx < BCAP) gsrc[(size_t)bb * BCAP + idx] = v;
    }
    return;
  }
  // ---- gemm block (MFMA) ----
  int r0 = (int)lo * GR;
  int w = t >> 6;            // wave id -> 16-row tile
  int l = t & 63;
  int lr = l & 15;           // A row-in-tile / B,D col-in-tile
  int g = l >> 4;            // k-group (8 elems each)
  int gr = r0 + w * 16 + lr;
  int grc = gr < N ? gr : N - 1;  // clamp; garbage rows never stored
  const float* __restrict__ Xrow = &X[(size_t)grc * RAW];
  const _Float16* __restrict__ Wb = &Wt[(size_t)lr * RAW];  // col lr of tile 0
  f32x4 acc0 = {0.f, 0.f, 0.f, 0.f};
  f32x4 acc1 = {0.f, 0.f, 0.f, 0.f};
  f32x4 acc2 = {0.f, 0.f, 0.f, 0.f};
  f32x4 acc3 = {0.f, 0.f, 0.f, 0.f};
#pragma unroll
  for (int kk = 0; kk < 8; ++kk) {
    int kb = kk * 32 + g * 8;
    float4 xa = *(const float4*)&Xrow[kb];
    float4 xb = *(const float4*)&Xrow[kb + 4];
    h8 a;
    a[0] = (_Float16)xa.x; a[1] = (_Float16)xa.y;
    a[2] = (_Float16)xa.z; a[3] = (_Float16)xa.w;
    a[4] = (_Float16)xb.x; a[5] = (_Float16)xb.y;
    a[6] = (_Float16)xb.z; a[7] = (_Float16)xb.w;
    h8 b0 = *(const h8*)&Wb[kb];                 // cols  0..15
    h8 b1 = *(const h8*)&Wb[16 * RAW + kb];      // cols 16..31
    h8 b2 = *(const h8*)&Wb[32 * RAW + kb];      // cols 32..47
    h8 b3 = *(const h8*)&Wb[48 * RAW + kb];      // cols 48..63
    acc0 = __builtin_amdgcn_mfma_f32_16x16x32_f16(a, b0, acc0, 0, 0, 0);
    acc1 = __builtin_amdgcn_mfma_f32_16x16x32_f16(a, b1, acc1, 0, 0, 0);
    acc2 = __builtin_amdgcn_mfma_f32_16x16x32_f16(a, b2, acc2, 0, 0, 0);
    acc3 = __builtin_amdgcn_mfma_f32_16x16x32_f16(a, b3, acc3, 0, 0, 0);
  }
#pragma unroll
  for (int r = 0; r < 4; ++r) {
    int row = r0 + w * 16 + g * 4 + r;
    if (row < N) {
      _Float16* yr = &Y[(size_t)row * FDIM];
      yr[lr] = (_Float16)acc0[r];
      yr[16 + lr] = (_Float16)acc1[r];
      yr[32 + lr] = (_Float16)acc2[r];
      int c3 = 48 + lr;   // col 55 -> ones; 56..63 acc is exactly 0 (Wt rows zero)
      yr[c3] = (c3 == NCLS) ? (_Float16)1.f : (_Float16)acc3[r];
    }
  }
}

// ---------------- build_scale: per-bucket CSR build + out-deg histogram + scaleY fold ----------------
// Block b owns nodes [b*256, b*256+255]: builds padded-CSR rows in a 32 KB LDS tile, counts this
// bucket's out-degrees from gsrc via LDS atomics (replaces 800k global atomics), writes csr_pad +
// fills + deg_o coalesced, then applies Y[n] *= inv_o(n) using the LDS histogram directly.
__global__ __launch_bounds__(256) void build_scale(
    const unsigned int* __restrict__ gedges, const int* __restrict__ gcur,
    const unsigned int* __restrict__ gsrc, const int* __restrict__ gcur2,
    unsigned short* __restrict__ csr_pad, int* __restrict__ fill_lo,
    int* __restrict__ fill_hi, int* __restrict__ deg_o,
    _Float16* __restrict__ Y, int N) {
  __shared__ __align__(16) unsigned short tile[BNODES * CAP];  // 32 KB
  __shared__ int flo[BNODES], fhi[BNODES], sdeg[BNODES];       // 3 KB
  int b = blockIdx.x;
  int t = threadIdx.x;
  flo[t] = 0; fhi[t] = 0; sdeg[t] = 0;
  __syncthreads();
  int cnt = min(gcur[b], BCAP);
  int cnt2 = min(gcur2[b], BCAP);
  int half = N >> 1;
  int nbeg = b << BSH;
  const unsigned int* ge = &gedges[(size_t)b * BCAP];
  for (int i = t; i < cnt; i += 256) {
    unsigned int v = ge[i];
    int s = (int)(v & 0xFFFFu);
    int ln = ((int)(v >> 16)) - nbeg;
    if (s < half) {
      int r = atomicAdd(&flo[ln], 1);
      if (r < CAP) tile[ln * CAP + r] = (unsigned short)s;
    } else {
      int r = atomicAdd(&fhi[ln], 1);
      int pos = CAP - 1 - r;
      if (pos >= 0) tile[ln * CAP + pos] = (unsigned short)s;
    }
  }
  const unsigned int* gs = &gsrc[(size_t)b * BCAP];
  for (int i = t; i < cnt2; i += 256)
    atomicAdd(&sdeg[(int)gs[i] - nbeg], 1);
  __syncthreads();
  int nn = min(BNODES, N - nbeg);
  if (nn <= 0) return;
  // coalesced CSR write-out: nn rows x 128 B (uninitialized slots are garbage, never read)
  const uint4* tl = (const uint4*)tile;
  uint4* gp = (uint4*)&csr_pad[(size_t)nbeg * CAP];
  for (int u = t; u < nn * 8; u += 256) gp[u] = tl[u];
  if (t < nn) {
    fill_lo[nbeg + t] = flo[t];
    fill_hi[nbeg + t] = fhi[t];
    deg_o[nbeg + t] = sdeg[t];
  }
  // fold scaleY for this node range: one h8 (16 B) per thread-iter; inv_o from LDS histogram
  for (int idx = t; idx < nn * 8; idx += 256) {
    int ln = idx >> 3;
    int c = (idx & 7) * 8;
    float w = 1.f / sqrtf(fmaxf((float)sdeg[ln], 1.f));
    h8 v = *(h8*)&Y[(size_t)(nbeg + ln) * FDIM + c];
#pragma unroll
    for (int q = 0; q < 8; ++q) v[q] = (_Float16)((float)v[q] * w);
    *(h8*)&Y[(size_t)(nbeg + ln) * FDIM + c] = v;
  }
}

// ---------------- agg1: two-sweep gather (round-3 proven form); B = s_mid(n)·Σ Y[s] ----------------
__global__ __launch_bounds__(256) void agg1_kernel(const _Float16* __restrict__ Y,
    const unsigned short* __restrict__ csr_pad,
    const int* __restrict__ fill_lo, const int* __restrict__ fill_hi,
    const int* __restrict__ deg_o, _Float16* __restrict__ B,
    float* __restrict__ u_out, int N) {
  int n = blockIdx.x * 32 + (threadIdx.x >> 3);
  int l = threadIdx.x & 7;                   // cols 8l..8l+7
  if (n >= N) return;
  int flo = min(fill_lo[n], CAP);
  int fhi = min(fill_hi[n], CAP);
  int fi = fill_lo[n] + fill_hi[n];
  const unsigned short* lst = &csr_pad[(size_t)n * CAP];
  float A0[8], A1[8];
#pragma unroll
  for (int q = 0; q < 8; ++q) { A0[q] = 0.f; A1[q] = 0.f; }
  int i = 0;
  for (; i + 3 < flo; i += 4) {
    int s0 = lst[i], s1 = lst[i + 1], s2 = lst[i + 2], s3 = lst[i + 3];
    h8 v0 = *(const h8*)&Y[(size_t)s0 * FDIM + 8 * l];
    h8 v1 = *(const h8*)&Y[(size_t)s1 * FDIM + 8 * l];
    h8 v2 = *(const h8*)&Y[(size_t)s2 * FDIM + 8 * l];
    h8 v3 = *(const h8*)&Y[(size_t)s3 * FDIM + 8 * l];
#pragma unroll
    for (int q = 0; q < 8; ++q) {
      A0[q] += (float)v0[q] + (float)v2[q];
      A1[q] += (float)v1[q] + (float)v3[q];
    }
  }
  for (; i < flo; ++i) {
    h8 v = *(const h8*)&Y[(size_t)lst[i] * FDIM + 8 * l];
#pragma unroll
    for (int q = 0; q < 8; ++q) A0[q] += (float)v[q];
  }
  i = CAP - fhi;
  for (; i + 3 < CAP; i += 4) {
    int s0 = lst[i], s1 = lst[i + 1], s2 = lst[i + 2], s3 = lst[i + 3];
    h8 v0 = *(const h8*)&Y[(size_t)s0 * FDIM + 8 * l];
    h8 v1 = *(const h8*)&Y[(size_t)s1 * FDIM + 8 * l];
    h8 v2 = *(const h8*)&Y[(size_t)s2 * FDIM + 8 * l];
    h8 v3 = *(const h8*)&Y[(size_t)s3 * FDIM + 8 * l];
#pragma unroll
    for (int q = 0; q < 8; ++q) {
      A0[q] += (float)v0[q] + (float)v2[q];
      A1[q] += (float)v1[q] + (float)v3[q];
    }
  }
  for (; i < CAP; ++i) {
    h8 v = *(const h8*)&Y[(size_t)lst[i] * FDIM + 8 * l];
#pragma unroll
    for (int q = 0; q < 8; ++q) A0[q] += (float)v[q];
  }
  float inv_i = 1.f / sqrtf(fmaxf((float)fi, 1.f));
  float inv_on = 1.f / sqrtf(fmaxf((float)deg_o[n], 1.f));
  float sm = inv_i * inv_on;                 // next layer's inv_o pre-applied
  h8 o;
#pragma unroll
  for (int q = 0; q < 8; ++q) o[q] = (_Float16)((A0[q] + A1[q]) * sm);
  *(h8*)&B[(size_t)n * FDIM + 8 * l] = o;
  if (l == 6) u_out[n] = (A0[7] + A1[7]) * inv_i;  // col 55 = lane 6, comp 7
}

// ---------------- agg2: two-sweep gather (round-3 proven form); bufA fp32 = inv_i(n)·Σ B[s] --------
__global__ __launch_bounds__(256) void agg2_kernel(const _Float16* __restrict__ B,
    const unsigned short* __restrict__ csr_pad,
    const int* __restrict__ fill_lo, const int* __restrict__ fill_hi,
    float* __restrict__ bufA, int N) {
  int n = blockIdx.x * 32 + (threadIdx.x >> 3);
  int l = threadIdx.x & 7;
  if (n >= N) return;
  int flo = min(fill_lo[n], CAP);
  int fhi = min(fill_hi[n], CAP);
  int fi = fill_lo[n] + fill_hi[n];
  const unsigned short* lst = &csr_pad[(size_t)n * CAP];
  float A0[8], A1[8];
#pragma unroll
  for (int q = 0; q < 8; ++q) { A0[q] = 0.f; A1[q] = 0.f; }
  int i = 0;
  for (; i + 3 < flo; i += 4) {
    int s0 = lst[i], s1 = lst[i + 1], s2 = lst[i + 2], s3 = lst[i + 3];
    h8 v0 = *(const h8*)&B[(size_t)s0 * FDIM + 8 * l];
    h8 v1 = *(const h8*)&B[(size_t)s1 * FDIM + 8 * l];
    h8 v2 = *(const h8*)&B[(size_t)s2 * FDIM + 8 * l];
    h8 v3 = *(const h8*)&B[(size_t)s3 * FDIM + 8 * l];
#pragma unroll
    for (int q = 0; q < 8; ++q) {
      A0[q] += (float)v0[q] + (float)v2[q];
      A1[q] += (float)v1[q] + (float)v3[q];
    }
  }
  for (; i < flo; ++i) {
    h8 v = *(const h8*)&B[(size_t)lst[i] * FDIM + 8 * l];
#pragma unroll
    for (int q = 0; q < 8; ++q) A0[q] += (float)v[q];
  }
  i = CAP - fhi;
  for (; i + 3 < CAP; i += 4) {
    int s0 = lst[i], s1 = lst[i + 1], s2 = lst[i + 2], s3 = lst[i + 3];
    h8 v0 = *(const h8*)&B[(size_t)s0 * FDIM + 8 * l];
    h8 v1 = *(const h8*)&B[(size_t)s1 * FDIM + 8 * l];
    h8 v2 = *(const h8*)&B[(size_t)s2 * FDIM + 8 * l];
    h8 v3 = *(const h8*)&B[(size_t)s3 * FDIM + 8 * l];
#pragma unroll
    for (int q = 0; q < 8; ++q) {
      A0[q] += (float)v0[q] + (float)v2[q];
      A1[q] += (float)v1[q] + (float)v3[q];
    }
  }
  for (; i < CAP; ++i) {
    h8 v = *(const h8*)&B[(size_t)lst[i] * FDIM + 8 * l];
#pragma unroll
    for (int q = 0; q < 8; ++q) A0[q] += (float)v[q];
  }
  float inv_i = 1.f / sqrtf(fmaxf((float)fi, 1.f));
  float4 o0, o1;
  o0.x = (A0[0] + A1[0]) * inv_i; o0.y = (A0[1] + A1[1]) * inv_i;
  o0.z = (A0[2] + A1[2]) * inv_i; o0.w = (A0[3] + A1[3]) * inv_i;
  o1.x = (A0[4] + A1[4]) * inv_i; o1.y = (A0[5] + A1[5]) * inv_i;
  o1.z = (A0[6] + A1[6]) * inv_i; o1.w = (A0[7] + A1[7]) * inv_i;
  *(float4*)&bufA[(size_t)n * FDIM + 8 * l] = o0;
  *(float4*)&bufA[(size_t)n * FDIM + 8 * l + 4] = o1;
}

// ---------------- pool + combine ----------------
__global__ __launch_bounds__(256) void pool_final(const float* __restrict__ feat,
    const float* __restrict__ u, const int* __restrict__ gid,
    const float* __restrict__ cvec, const float* __restrict__ bc,
    float* __restrict__ out, int N, int G) {
  __shared__ int sb[2];
  __shared__ float red[4][64];
  int g = blockIdx.x;
  int t = threadIdx.x;
  int rg = t >> 6, j = t & 63;
  if (t < 2) {
    int target = g + t;
    int lo = 0, hi = N;
    while (lo < hi) {
      int mid = (lo + hi) >> 1;
      if (gid[mid] < target) lo = mid + 1; else hi = mid;
    }
    sb[t] = lo;
  }
  __syncthreads();
  int beg = sb[0], end = sb[1];
  float acc = 0.f;
  for (int r = beg + rg; r < end; r += 4) {
    float v;
    if (j < NCLS + 1) v = feat[(size_t)r * FDIM + j];
    else if (j == NCLS + 1) v = u[r];
    else v = 0.f;
    acc += v;
  }
  red[rg][j] = acc;
  __syncthreads();
  if (rg == 0) {
    float s = red[0][j] + red[1][j] + red[2][j] + red[3][j];
    float cnt = (float)(end - beg);
    float inv = 1.f / fmaxf(cnt, 1.f);
    red[1][j] = s * inv;
  }
  __syncthreads();
  if (rg == 0 && j < NCLS) {
    float vbar = red[1][NCLS];
    float ubar = red[1][NCLS + 1];
    float ind = (end > beg) ? 1.f : 0.f;
    out[g * NCLS + j] = red[1][j] + vbar * cvec[j] + ubar * cvec[64 + j]
                        + ind * cvec[128 + j] + bc[j];
  }
}

extern "C" void kernel_launch(void* const* d_in, const int* in_sizes, int n_in,
                              void* d_out, int out_size, void* d_ws, size_t ws_size,
                              hipStream_t stream) {
  const float* X     = (const float*)d_in[0];
  const int*   src   = (const int*)d_in[1];
  const int*   dst   = (const int*)d_in[2];
  const int*   gid   = (const int*)d_in[3];
  const float* W_ext = (const float*)d_in[4];
  const float* b_ext = (const float*)d_in[5];
  const float* W1    = (const float*)d_in[6];
  const float* b1    = (const float*)d_in[7];
  const float* W2    = (const float*)d_in[8];
  const float* b2    = (const float*)d_in[9];
  const float* Wc    = (const float*)d_in[10];
  const float* bc    = (const float*)d_in[11];
  float* out = (float*)d_out;

  int N = in_sizes[0] / RAW;
  int E = in_sizes[1];
  int G = out_size / NCLS;
  int nb = (N + BNODES - 1) >> BSH;   // 196 buckets for N=50000

  char* p = (char*)d_ws;
  auto alloc = [&](size_t b) { char* r = p; p += (b + 255) & ~(size_t)255; return r; };

  int*            gcur    = (int*)alloc(NBUK * 4);
  int*            gcur2   = (int*)alloc(NBUK * 4);
  size_t zero_span = (size_t)(p - (char*)gcur);   // 2 KB: only the bucket cursors need zeroing
  int*            deg_o   = (int*)alloc((size_t)N * 4);
  int*            fill_lo = (int*)alloc((size_t)N * 4);
  int*            fill_hi = (int*)alloc((size_t)N * 4);
  unsigned short* csr_pad = (unsigned short*)alloc((size_t)N * CAP * 2);
  unsigned int*   gedges  = (unsigned int*)alloc((size_t)nb * BCAP * 4);
  unsigned int*   gsrc    = (unsigned int*)alloc((size_t)nb * BCAP * 4);
  float*          T1p     = (float*)alloc(LAT * 64 * 4);
  float*          T2p     = (float*)alloc(LAT * 64 * 4);
  _Float16*       Wt      = (_Float16*)alloc((size_t)64 * RAW * 2);
  float*          cvec    = (float*)alloc(192 * 4);
  float*          u_arr   = (float*)alloc((size_t)N * 4);
  _Float16*       Y       = (_Float16*)alloc((size_t)N * FDIM * 2);
  _Float16*       B       = (_Float16*)alloc((size_t)N * FDIM * 2);
  float*          bufA    = (float*)alloc((size_t)N * FDIM * 4);

  hipMemsetAsync(gcur, 0, zero_span, stream);

  w1_kernel<<<(LAT + 1 + 3) / 4, 256, 0, stream>>>(W2, b2, Wc, T1p, cvec);
  w2_kernel<<<(LAT + 1 + 3) / 4, 256, 0, stream>>>(W1, b1, T1p, T2p, cvec);
  w3_kernel<<<(RAW + 1 + 3) / 4, 256, 0, stream>>>(W_ext, b_ext, T2p, Wt, cvec);

  int nE = (E + EPB - 1) / EPB;
  int nGm = (N + GR - 1) / GR;
  mega<<<nE + nGm, 256, 0, stream>>>(src, dst, gcur, gcur2, gedges, gsrc, E,
                                     X, Wt, Y, N, nE, nGm);

  build_scale<<<nb, 256, 0, stream>>>(gedges, gcur, gsrc, gcur2, csr_pad,
                                      fill_lo, fill_hi, deg_o, Y, N);

  int aggGrid = (N + 31) / 32;
  agg1_kernel<<<aggGrid, 256, 0, stream>>>(Y, csr_pad, fill_lo, fill_hi, deg_o, B, u_arr, N);
  agg2_kernel<<<aggGrid, 256, 0, stream>>>(B, csr_pad, fill_lo, fill_hi, bufA, N);

  pool_final<<<G, 256, 0, stream>>>(bufA, u_arr, gid, cvec, bc, out, N, G);
}